// Round 5
// baseline (622.831 us; speedup 1.0000x reference)
//
#include <hip/hip_runtime.h>

#define N_NODES 131072
#define N_EDGES 1048576
#define TOT_EDG (N_NODES + N_EDGES)
#define G_GRAPHS 128
#define NPG 1024

typedef unsigned short u16;
typedef unsigned int u32;
typedef __attribute__((ext_vector_type(8))) short bh8;
typedef __attribute__((ext_vector_type(4))) float f4;

__device__ __forceinline__ float bcf(u32 u){ return __builtin_bit_cast(float, u); }
__device__ __forceinline__ u32 bcu(float f){ return __builtin_bit_cast(u32, f); }

// round-half-up bf16: (u + 0x8000) >> 16 ; pack pair with one v_perm_b32
__device__ __forceinline__ u16 f2b(float f){ return (u16)((bcu(f) + 0x8000u) >> 16); }
__device__ __forceinline__ u32 pk_rn(float lo, float hi){
    u32 a = bcu(lo) + 0x8000u;
    u32 b = bcu(hi) + 0x8000u;
    return __builtin_amdgcn_perm(b, a, 0x07060302u);   // D = {b.hi16, a.hi16}
}

// ---------------- fused: weight transposes (blocks 0..255) + edge histogram (256..1279) ----------------
__global__ __launch_bounds__(256) void wtrans_hist(const float* __restrict__ W1, const float* __restrict__ W2,
                           const float* __restrict__ W3,
                           u16* __restrict__ Wt1, u16* __restrict__ Wt2, u16* __restrict__ Wt3,
                           const int* __restrict__ dst, int* __restrict__ hist){
    int b = blockIdx.x, t = threadIdx.x;
    if (b < 128){                 // W1: 256x128 -> Wt1[128][256]
        int idx = b*256 + t; int c = idx >> 8, k = idx & 255;
        Wt1[idx] = f2b(W1[k*128 + c]);
    } else if (b < 192){          // W2: 128x128
        int idx = (b-128)*256 + t; int c = idx >> 7, k = idx & 127;
        Wt2[idx] = f2b(W2[k*128 + c]);
    } else if (b < 256){          // W3: 128x128
        int idx = (b-192)*256 + t; int c = idx >> 7, k = idx & 127;
        Wt3[idx] = f2b(W3[k*128 + c]);
    } else {
        __shared__ int h[128];
        int bb = b - 256;
        if (t < 128) h[t] = 0;
        __syncthreads();
        int base = bb*1024 + t;
        #pragma unroll
        for (int i = 0; i < 4; i++) atomicAdd(&h[dst[base + i*256] >> 10], 1);
        __syncthreads();
        if (t < 128) hist[bb*128 + t] = h[t];
    }
}

// A2: per-bucket column exclusive scan over 1024 blocks -> baseRel[blk][bucket], total[bucket]
__global__ __launch_bounds__(256) void bin_scan(const int* __restrict__ hist,
                                                int* __restrict__ baseRel, int* __restrict__ total){
    int bk = blockIdx.x, t = threadIdx.x;   // 128 blocks
    int v[4]; int s = 0;
    #pragma unroll
    for (int i = 0; i < 4; i++){ v[i] = hist[(t*4+i)*128 + bk]; s += v[i]; }
    __shared__ int l[256];
    l[t] = s; __syncthreads();
    for (int off = 1; off < 256; off <<= 1){
        int u = (t >= off) ? l[t-off] : 0;
        __syncthreads();
        l[t] += u;
        __syncthreads();
    }
    int run = l[t] - s;
    #pragma unroll
    for (int i = 0; i < 4; i++){ baseRel[(t*4+i)*128 + bk] = run; run += v[i]; }
    if (t == 255) total[bk] = run;
}

// A2b: scan 128 bucket totals -> bstart (edge space), brow (col space incl self loops)
__global__ void bucket_scan(const int* __restrict__ total, int* __restrict__ bstart,
                            int* __restrict__ brow, int* __restrict__ row_ptr){
    int t = threadIdx.x;   // 128
    __shared__ int l[128];
    int v = total[t];
    l[t] = v; __syncthreads();
    for (int off = 1; off < 128; off <<= 1){
        int u = (t >= off) ? l[t-off] : 0;
        __syncthreads();
        l[t] += u;
        __syncthreads();
    }
    int e = l[t] - v;
    bstart[t] = e;
    brow[t] = e + t*1024;          // + self loops of preceding buckets
    if (t == 127) row_ptr[N_NODES] = TOT_EDG;
}

// A3: scatter (src,dst) into bucket-ordered array; per-block contiguous runs per bucket.
__global__ __launch_bounds__(256) void bin_scatter(const int* __restrict__ src, const int* __restrict__ dst,
                           const int* __restrict__ baseRel, const int* __restrict__ bstart,
                           uint2* __restrict__ binned){
    __shared__ int cur[128];
    __shared__ int bs[128];
    int b = blockIdx.x, t = threadIdx.x;
    if (t < 128){ cur[t] = baseRel[b*128 + t]; bs[t] = bstart[t]; }
    __syncthreads();
    #pragma unroll
    for (int i = 0; i < 4; i++){
        int e = b*1024 + i*256 + t;
        int s = src[e], d = dst[e];
        int bk = d >> 10;
        int r = atomicAdd(&cur[bk], 1);
        uint2 o; o.x = (u32)s; o.y = (u32)d;
        binned[bs[bk] + r] = o;
    }
}

// B: one block per bucket: LDS counts + LDS scan -> row_ptr, self loops, col scatter (L2-local window)
__global__ __launch_bounds__(256) void bucket_csr(const uint2* __restrict__ binned,
                           const int* __restrict__ bstart, const int* __restrict__ total,
                           const int* __restrict__ brow,
                           int* __restrict__ row_ptr, int* __restrict__ colb){
    int b = blockIdx.x, t = threadIdx.x;
    __shared__ int cnt[1024];
    __shared__ int l[256];
    int ebeg = bstart[b], ecnt = total[b], rbase = brow[b];
    for (int i = t; i < 1024; i += 256) cnt[i] = 1;      // self loop
    __syncthreads();
    for (int i = t; i < ecnt; i += 256){
        uint2 e = binned[ebeg + i];
        atomicAdd(&cnt[e.y & 1023], 1);
    }
    __syncthreads();
    int v0 = cnt[t*4], v1 = cnt[t*4+1], v2 = cnt[t*4+2], v3 = cnt[t*4+3];
    int s = v0+v1+v2+v3;
    l[t] = s; __syncthreads();
    for (int off = 1; off < 256; off <<= 1){
        int u = (t >= off) ? l[t-off] : 0;
        __syncthreads();
        l[t] += u;
        __syncthreads();
    }
    int excl = l[t] - s;
    int node0 = b*1024 + t*4;
    int p0 = rbase + excl;
    int p1 = p0 + v0, p2 = p1 + v1, p3 = p2 + v2;
    row_ptr[node0]   = p0; colb[p0] = node0;
    row_ptr[node0+1] = p1; colb[p1] = node0+1;
    row_ptr[node0+2] = p2; colb[p2] = node0+2;
    row_ptr[node0+3] = p3; colb[p3] = node0+3;
    __syncthreads();
    cnt[t*4] = p0+1; cnt[t*4+1] = p1+1; cnt[t*4+2] = p2+1; cnt[t*4+3] = p3+1;
    __syncthreads();
    for (int i = t; i < ecnt; i += 256){
        uint2 e = binned[ebeg + i];
        int p = atomicAdd(&cnt[e.y & 1023], 1);
        colb[p] = (int)e.x;
    }
}

// ---------------- MFMA GEMM with fused es/ed epilogue ----------------
template<int K, bool AF32>
__global__ __launch_bounds__(256) void gat_gemm(const void* __restrict__ A_,
                                                const u16* __restrict__ Bt,   // [128][K]
                                                const float* __restrict__ asrc,
                                                const float* __restrict__ adst,
                                                u16* __restrict__ Hb,
                                                float* __restrict__ es, float* __restrict__ ed){
    constexpr int SA = 40;                 // padded LDS row stride (bf16 units)
    __shared__ u16 As[128*SA];
    __shared__ u16 Bs[128*SA];
    const int t = threadIdx.x;
    const int wave = t >> 6, lane = t & 63, quad = lane >> 4, m16 = lane & 15;
    const long rowBase = (long)blockIdx.x * 128;
    const int r = t >> 1, c0 = (t & 1) * 16;   // staging: 16 elems / thread
    f4 acc[2][8] = {};

    for (int kk = 0; kk < K; kk += 32){
        if (AF32){
            const float* A = (const float*)A_;
            const float* src = A + (rowBase + r) * (long)K + kk + c0;
            float4 a0 = *(const float4*)(src+0);
            float4 a1 = *(const float4*)(src+4);
            float4 a2 = *(const float4*)(src+8);
            float4 a3 = *(const float4*)(src+12);
            uint4 v0, v1;
            v0.x = pk_rn(a0.x, a0.y); v0.y = pk_rn(a0.z, a0.w);
            v0.z = pk_rn(a1.x, a1.y); v0.w = pk_rn(a1.z, a1.w);
            v1.x = pk_rn(a2.x, a2.y); v1.y = pk_rn(a2.z, a2.w);
            v1.z = pk_rn(a3.x, a3.y); v1.w = pk_rn(a3.z, a3.w);
            *(uint4*)&As[r*SA + c0]     = v0;
            *(uint4*)&As[r*SA + c0 + 8] = v1;
        } else {
            const u16* A = (const u16*)A_;
            const u16* src = A + (rowBase + r) * (long)K + kk + c0;
            uint4 v0 = *(const uint4*)(src);
            uint4 v1 = *(const uint4*)(src + 8);
            *(uint4*)&As[r*SA + c0]     = v0;
            *(uint4*)&As[r*SA + c0 + 8] = v1;
        }
        {
            const u16* src = Bt + r * (long)K + kk + c0;
            uint4 v0 = *(const uint4*)(src);
            uint4 v1 = *(const uint4*)(src + 8);
            *(uint4*)&Bs[r*SA + c0]     = v0;
            *(uint4*)&Bs[r*SA + c0 + 8] = v1;
        }
        __syncthreads();
        bh8 af0 = *(const bh8*)&As[(wave*32      + m16)*SA + quad*8];
        bh8 af1 = *(const bh8*)&As[(wave*32 + 16 + m16)*SA + quad*8];
        #pragma unroll
        for (int ct = 0; ct < 8; ct++){
            bh8 bw = *(const bh8*)&Bs[(ct*16 + m16)*SA + quad*8];
            acc[0][ct] = __builtin_amdgcn_mfma_f32_16x16x32_bf16(bw, af0, acc[0][ct], 0,0,0);
            acc[1][ct] = __builtin_amdgcn_mfma_f32_16x16x32_bf16(bw, af1, acc[1][ct], 0,0,0);
        }
        __syncthreads();
    }
    // epilogue: packed stores + fused es/ed
    #pragma unroll
    for (int nt2 = 0; nt2 < 2; nt2++){
        long node = rowBase + wave*32 + nt2*16 + m16;
        float ps = 0.f, pd = 0.f;
        #pragma unroll
        for (int ct = 0; ct < 8; ct++){
            f4 a = acc[nt2][ct];
            float4 av = *(const float4*)(asrc + ct*16 + quad*4);
            float4 dv = *(const float4*)(adst + ct*16 + quad*4);
            ps += a.x*av.x + a.y*av.y + a.z*av.z + a.w*av.w;
            pd += a.x*dv.x + a.y*dv.y + a.z*dv.z + a.w*dv.w;
            uint2 o;
            o.x = pk_rn(a.x, a.y);
            o.y = pk_rn(a.z, a.w);
            *(uint2*)(Hb + node*128 + ct*16 + quad*4) = o;
        }
        ps += __shfl_xor(ps, 16); ps += __shfl_xor(ps, 32);
        pd += __shfl_xor(pd, 16); pd += __shfl_xor(pd, 32);
        if (quad == 0){ es[node] = ps; ed[node] = pd; }
    }
}

// ---------------- softmax-weighted aggregation: wave/node, 8 groups x 8 lanes x 2-deep ----------------
// Each lane covers 16 channels (32B); up to 16 row-gathers (4KB) in flight per wave.
__global__ __launch_bounds__(256) void gat_agg(const u16* __restrict__ Hb,
                        const float* __restrict__ es, const float* __restrict__ ed,
                        const int* __restrict__ row_ptr, const int* __restrict__ colv,
                        const float* __restrict__ bias, u16* __restrict__ Xb){
    int t = threadIdx.x, wave = t >> 6, lane = t & 63;
    int grp = lane >> 3, cl = lane & 7;       // 8 edge-groups x 8 channel-lanes
    int n = blockIdx.x * 4 + wave;
    int beg = row_ptr[n], end = row_ptr[n+1];
    float edn = ed[n];
    float den = 0.f;
    float a[16] = {};
    int j = beg + grp;
    for (; j + 8 < end; j += 16){
        int s0 = colv[j], s1 = colv[j+8];
        float q0 = es[s0] + edn, q1 = es[s1] + edn;
        const uint4* p0 = (const uint4*)(Hb + (long)s0*128 + cl*16);
        const uint4* p1 = (const uint4*)(Hb + (long)s1*128 + cl*16);
        uint4 h00 = p0[0], h01 = p0[1];
        uint4 h10 = p1[0], h11 = p1[1];
        q0 = fmaxf(q0, 0.f) + 0.2f*fminf(q0, 0.f);
        q1 = fmaxf(q1, 0.f) + 0.2f*fminf(q1, 0.f);
        float x0 = __expf(q0), x1 = __expf(q1);
        den += x0 + x1;
        a[0]  += x0*bcf(h00.x << 16) + x1*bcf(h10.x << 16);
        a[1]  += x0*bcf(h00.x & 0xffff0000u) + x1*bcf(h10.x & 0xffff0000u);
        a[2]  += x0*bcf(h00.y << 16) + x1*bcf(h10.y << 16);
        a[3]  += x0*bcf(h00.y & 0xffff0000u) + x1*bcf(h10.y & 0xffff0000u);
        a[4]  += x0*bcf(h00.z << 16) + x1*bcf(h10.z << 16);
        a[5]  += x0*bcf(h00.z & 0xffff0000u) + x1*bcf(h10.z & 0xffff0000u);
        a[6]  += x0*bcf(h00.w << 16) + x1*bcf(h10.w << 16);
        a[7]  += x0*bcf(h00.w & 0xffff0000u) + x1*bcf(h10.w & 0xffff0000u);
        a[8]  += x0*bcf(h01.x << 16) + x1*bcf(h11.x << 16);
        a[9]  += x0*bcf(h01.x & 0xffff0000u) + x1*bcf(h11.x & 0xffff0000u);
        a[10] += x0*bcf(h01.y << 16) + x1*bcf(h11.y << 16);
        a[11] += x0*bcf(h01.y & 0xffff0000u) + x1*bcf(h11.y & 0xffff0000u);
        a[12] += x0*bcf(h01.z << 16) + x1*bcf(h11.z << 16);
        a[13] += x0*bcf(h01.z & 0xffff0000u) + x1*bcf(h11.z & 0xffff0000u);
        a[14] += x0*bcf(h01.w << 16) + x1*bcf(h11.w << 16);
        a[15] += x0*bcf(h01.w & 0xffff0000u) + x1*bcf(h11.w & 0xffff0000u);
    }
    if (j < end){
        int s = colv[j];
        float e = es[s] + edn;
        const uint4* p0 = (const uint4*)(Hb + (long)s*128 + cl*16);
        uint4 h00 = p0[0], h01 = p0[1];
        e = fmaxf(e, 0.f) + 0.2f*fminf(e, 0.f);
        float ex = __expf(e);
        den += ex;
        a[0]  += ex*bcf(h00.x << 16);  a[1]  += ex*bcf(h00.x & 0xffff0000u);
        a[2]  += ex*bcf(h00.y << 16);  a[3]  += ex*bcf(h00.y & 0xffff0000u);
        a[4]  += ex*bcf(h00.z << 16);  a[5]  += ex*bcf(h00.z & 0xffff0000u);
        a[6]  += ex*bcf(h00.w << 16);  a[7]  += ex*bcf(h00.w & 0xffff0000u);
        a[8]  += ex*bcf(h01.x << 16);  a[9]  += ex*bcf(h01.x & 0xffff0000u);
        a[10] += ex*bcf(h01.y << 16);  a[11] += ex*bcf(h01.y & 0xffff0000u);
        a[12] += ex*bcf(h01.z << 16);  a[13] += ex*bcf(h01.z & 0xffff0000u);
        a[14] += ex*bcf(h01.w << 16);  a[15] += ex*bcf(h01.w & 0xffff0000u);
    }
    #pragma unroll
    for (int k = 0; k < 16; k++){
        a[k] += __shfl_xor(a[k], 8);
        a[k] += __shfl_xor(a[k], 16);
        a[k] += __shfl_xor(a[k], 32);
    }
    den += __shfl_xor(den, 8); den += __shfl_xor(den, 16); den += __shfl_xor(den, 32);
    if (grp == 0){
        float inv = 1.0f / (den + 1e-16f);
        float4 b0 = *(const float4*)(bias + cl*16);
        float4 b1 = *(const float4*)(bias + cl*16 + 4);
        float4 b2 = *(const float4*)(bias + cl*16 + 8);
        float4 b3 = *(const float4*)(bias + cl*16 + 12);
        uint4 o0, o1;
        o0.x = pk_rn(fmaxf(a[0]*inv + b0.x, 0.f),  fmaxf(a[1]*inv + b0.y, 0.f));
        o0.y = pk_rn(fmaxf(a[2]*inv + b0.z, 0.f),  fmaxf(a[3]*inv + b0.w, 0.f));
        o0.z = pk_rn(fmaxf(a[4]*inv + b1.x, 0.f),  fmaxf(a[5]*inv + b1.y, 0.f));
        o0.w = pk_rn(fmaxf(a[6]*inv + b1.z, 0.f),  fmaxf(a[7]*inv + b1.w, 0.f));
        o1.x = pk_rn(fmaxf(a[8]*inv + b2.x, 0.f),  fmaxf(a[9]*inv + b2.y, 0.f));
        o1.y = pk_rn(fmaxf(a[10]*inv + b2.z, 0.f), fmaxf(a[11]*inv + b2.w, 0.f));
        o1.z = pk_rn(fmaxf(a[12]*inv + b3.x, 0.f), fmaxf(a[13]*inv + b3.y, 0.f));
        o1.w = pk_rn(fmaxf(a[14]*inv + b3.z, 0.f), fmaxf(a[15]*inv + b3.w, 0.f));
        uint4* dst = (uint4*)(Xb + (long)n*128 + cl*16);
        dst[0] = o0;
        dst[1] = o1;
    }
}

// ---------------- partial per-graph max pool: block = 128 nodes ----------------
__global__ void pool_part(const u16* __restrict__ Xb, float* __restrict__ pooled8){
    int b = blockIdx.x;            // 1024 = G*8 segments
    int t = threadIdx.x;           // 256
    int wave = t >> 6, lane = t & 63, grp = lane >> 4, cl = lane & 15;
    long base = (long)b * 128;
    float m[8] = {};
    for (int i = 0; i < 8; i++){
        long node = base + wave*32 + i*4 + grp;
        uint4 hv = *(const uint4*)(Xb + node*128 + cl*8);
        m[0] = fmaxf(m[0], bcf(hv.x << 16));  m[1] = fmaxf(m[1], bcf(hv.x & 0xffff0000u));
        m[2] = fmaxf(m[2], bcf(hv.y << 16));  m[3] = fmaxf(m[3], bcf(hv.y & 0xffff0000u));
        m[4] = fmaxf(m[4], bcf(hv.z << 16));  m[5] = fmaxf(m[5], bcf(hv.z & 0xffff0000u));
        m[6] = fmaxf(m[6], bcf(hv.w << 16));  m[7] = fmaxf(m[7], bcf(hv.w & 0xffff0000u));
    }
    #pragma unroll
    for (int k = 0; k < 8; k++){
        m[k] = fmaxf(m[k], __shfl_xor(m[k], 16));
        m[k] = fmaxf(m[k], __shfl_xor(m[k], 32));
    }
    __shared__ float red[4][128];
    if (grp == 0){
        #pragma unroll
        for (int k = 0; k < 8; k++) red[wave][cl*8 + k] = m[k];
    }
    __syncthreads();
    if (t < 128){
        float v = fmaxf(fmaxf(red[0][t], red[1][t]), fmaxf(red[2][t], red[3][t]));
        pooled8[(long)b*128 + t] = v;
    }
}

// ---------------- tail: 8-way pool reduce, news, h0, eh/ee projections ----------------
__global__ void tail2(const float* __restrict__ x, const float* __restrict__ pooled8,
                      const float* __restrict__ Wn, const float* __restrict__ bn,
                      const float* __restrict__ W0, const float* __restrict__ b0,
                      const float* __restrict__ Wa1, const float* __restrict__ Wa2,
                      float* eh1, float* ee1, float* eh2, float* ee2){
    int g = blockIdx.x, c = threadIdx.x;  // 128 threads
    __shared__ float xr[256], pr[128], nr[128], hr[128];
    const float* xroot = x + (size_t)g * NPG * 256;   // root = first node of graph
    xr[c] = xroot[c]; xr[c+128] = xroot[c+128];
    {
        const float* pg = pooled8 + (long)g*8*128 + c;
        float v = pg[0];
        for (int s2 = 1; s2 < 8; s2++) v = fmaxf(v, pg[s2*128]);
        pr[c] = v;
    }
    __syncthreads();
    float a = bn[c];
    for (int k = 0; k < 256; k++) a += xr[k] * Wn[k*128 + c];
    a = fmaxf(a, 0.f);
    float b = b0[c];
    for (int k = 0; k < 128; k++) b += pr[k] * W0[k*128 + c];
    b = fmaxf(b, 0.f);
    nr[c] = a; hr[c] = b;
    __syncthreads();
    if (c < 64){
        int o = c; float s1 = 0.f, s2 = 0.f;
        for (int k = 0; k < 128; k++){ s1 += hr[k]*Wa1[k*64 + o]; s2 += nr[k]*Wa2[k*64 + o]; }
        eh1[g*64 + o] = s1; eh2[g*64 + o] = s2;
    } else {
        int o = c - 64; float s1 = 0.f, s2 = 0.f;
        for (int k = 0; k < 128; k++){ s1 += nr[k]*Wa1[(128+k)*64 + o]; s2 += hr[k]*Wa2[(128+k)*64 + o]; }
        ee1[g*64 + o] = s1; ee2[g*64 + o] = s2;
    }
}

// ---------------- tail: energies + final linear + sigmoid (block per row i) ----------------
__global__ void tail3(const float* __restrict__ eh1, const float* __restrict__ ee1,
                      const float* __restrict__ eh2, const float* __restrict__ ee2,
                      const float* __restrict__ ba1, const float* __restrict__ v1,
                      const float* __restrict__ ba2, const float* __restrict__ v2,
                      const float* __restrict__ Wl, const float* __restrict__ bl,
                      float* out){
    int i = blockIdx.x, t = threadIdx.x;   // 256 threads
    __shared__ float e1i[64], e2i[64], fh[128], fn[128];
    if (t < 64) e1i[t] = eh1[i*64 + t];
    else if (t < 128) e2i[t-64] = eh2[i*64 + (t-64)];
    __syncthreads();
    if (t < 128){
        int j = t; float s = 0.f;
        for (int o = 0; o < 64; o++) s += tanhf(e1i[o] + ee1[j*64+o] + ba1[o]) * v1[o];
        fh[j] = s;
    } else {
        int j = t - 128; float s = 0.f;
        for (int o = 0; o < 64; o++) s += tanhf(e2i[o] + ee2[j*64+o] + ba2[o]) * v2[o];
        fn[j] = s;
    }
    __syncthreads();
    if (t < 64){
        int o = t; float s = bl[o];
        for (int j = 0; j < 128; j++) s += fh[j]*Wl[j*64+o] + fn[j]*Wl[(128+j)*64+o];
        out[i*64 + o] = 1.0f / (1.0f + expf(-s));
    }
}

extern "C" void kernel_launch(void* const* d_in, const int* in_sizes, int n_in,
                              void* d_out, int out_size, void* d_ws, size_t ws_size,
                              hipStream_t stream){
    const float* x   = (const float*)d_in[0];
    const int* eidx  = (const int*)d_in[1];
    const int* esrc  = eidx;
    const int* edst  = eidx + N_EDGES;
    const float* W1  = (const float*)d_in[3];
    const float* as1 = (const float*)d_in[4];
    const float* ad1 = (const float*)d_in[5];
    const float* b1  = (const float*)d_in[6];
    const float* W2  = (const float*)d_in[7];
    const float* as2 = (const float*)d_in[8];
    const float* ad2 = (const float*)d_in[9];
    const float* b2  = (const float*)d_in[10];
    const float* W3  = (const float*)d_in[11];
    const float* as3 = (const float*)d_in[12];
    const float* ad3 = (const float*)d_in[13];
    const float* b3  = (const float*)d_in[14];
    const float* Wn  = (const float*)d_in[15];
    const float* bn  = (const float*)d_in[16];
    const float* W0  = (const float*)d_in[17];
    const float* b0  = (const float*)d_in[18];
    const float* Wl  = (const float*)d_in[19];
    const float* bl  = (const float*)d_in[20];
    const float* Wa1 = (const float*)d_in[21];
    const float* ba1 = (const float*)d_in[22];
    const float* v1  = (const float*)d_in[23];
    const float* Wa2 = (const float*)d_in[24];
    const float* ba2 = (const float*)d_in[25];
    const float* v2  = (const float*)d_in[26];
    float* out = (float*)d_out;

    char* p = (char*)d_ws;
    auto take = [&](size_t b)->char*{ char* q = p; p += (b + 255) & ~(size_t)255; return q; };
    u16* Hb      = (u16*)take((size_t)N_NODES*128*2);
    u16* Xb      = (u16*)take((size_t)N_NODES*128*2);
    float* es    = (float*)take((size_t)N_NODES*4);
    float* ed    = (float*)take((size_t)N_NODES*4);
    int* row_ptr = (int*)take((size_t)(N_NODES+1)*4);
    int* colb    = (int*)take((size_t)TOT_EDG*4);
    uint2* binned= (uint2*)take((size_t)N_EDGES*8);
    int* hist    = (int*)take((size_t)1024*128*4);
    int* baseRel = (int*)take((size_t)1024*128*4);
    int* total   = (int*)take(128*4);
    int* bstart  = (int*)take(128*4);
    int* brow    = (int*)take(128*4);
    u16* Wt1     = (u16*)take(128*256*2);
    u16* Wt2     = (u16*)take(128*128*2);
    u16* Wt3     = (u16*)take(128*128*2);
    float* pooled8=(float*)take((size_t)1024*128*4);
    float* eh1   = (float*)take(128*64*4);
    float* ee1   = (float*)take(128*64*4);
    float* eh2   = (float*)take(128*64*4);
    float* ee2   = (float*)take(128*64*4);

    // weight transposes + histogram, single launch
    wtrans_hist<<<1280, 256, 0, stream>>>(W1, W2, W3, Wt1, Wt2, Wt3, edst, hist);

    // binned CSR build (by dst, self-loop in slot 0)
    bin_scan<<<128, 256, 0, stream>>>(hist, baseRel, total);
    bucket_scan<<<1, 128, 0, stream>>>(total, bstart, brow, row_ptr);
    bin_scatter<<<1024, 256, 0, stream>>>(esrc, edst, baseRel, bstart, binned);
    bucket_csr<<<128, 256, 0, stream>>>(binned, bstart, total, brow, row_ptr, colb);

    // layer 1
    gat_gemm<256, true><<<N_NODES/128, 256, 0, stream>>>(x, Wt1, as1, ad1, Hb, es, ed);
    gat_agg<<<N_NODES/4, 256, 0, stream>>>(Hb, es, ed, row_ptr, colb, b1, Xb);
    // layer 2
    gat_gemm<128, false><<<N_NODES/128, 256, 0, stream>>>(Xb, Wt2, as2, ad2, Hb, es, ed);
    gat_agg<<<N_NODES/4, 256, 0, stream>>>(Hb, es, ed, row_ptr, colb, b2, Xb);
    // layer 3
    gat_gemm<128, false><<<N_NODES/128, 256, 0, stream>>>(Xb, Wt3, as3, ad3, Hb, es, ed);
    gat_agg<<<N_NODES/4, 256, 0, stream>>>(Hb, es, ed, row_ptr, colb, b3, Xb);

    // tail
    pool_part<<<1024, 256, 0, stream>>>(Xb, pooled8);
    tail2<<<G_GRAPHS, 128, 0, stream>>>(x, pooled8, Wn, bn, W0, b0, Wa1, Wa2, eh1, ee1, eh2, ee2);
    tail3<<<G_GRAPHS, 256, 0, stream>>>(eh1, ee1, eh2, ee2, ba1, v1, ba2, v2, Wl, bl, out);
}

// Round 6
// 597.891 us; speedup vs baseline: 1.0417x; 1.0417x over previous
//
#include <hip/hip_runtime.h>

#define N_NODES 131072
#define N_EDGES 1048576
#define TOT_EDG (N_NODES + N_EDGES)
#define G_GRAPHS 128
#define NPG 1024

typedef unsigned short u16;
typedef unsigned int u32;
typedef __attribute__((ext_vector_type(8))) short bh8;
typedef __attribute__((ext_vector_type(4))) float f4;

__device__ __forceinline__ float bcf(u32 u){ return __builtin_bit_cast(float, u); }
__device__ __forceinline__ u32 bcu(float f){ return __builtin_bit_cast(u32, f); }

// round-half-up bf16: (u + 0x8000) >> 16 ; pack pair with one v_perm_b32
__device__ __forceinline__ u16 f2b(float f){ return (u16)((bcu(f) + 0x8000u) >> 16); }
__device__ __forceinline__ u32 pk_rn(float lo, float hi){
    u32 a = bcu(lo) + 0x8000u;
    u32 b = bcu(hi) + 0x8000u;
    return __builtin_amdgcn_perm(b, a, 0x07060302u);   // D = {b.hi16, a.hi16}
}

// ---------------- fused: weight transposes (blocks 0..255) + edge histogram (256..1279) ----------------
__global__ __launch_bounds__(256) void wtrans_hist(const float* __restrict__ W1, const float* __restrict__ W2,
                           const float* __restrict__ W3,
                           u16* __restrict__ Wt1, u16* __restrict__ Wt2, u16* __restrict__ Wt3,
                           const int* __restrict__ dst, int* __restrict__ hist){
    int b = blockIdx.x, t = threadIdx.x;
    if (b < 128){                 // W1: 256x128 -> Wt1[128][256]
        int idx = b*256 + t; int c = idx >> 8, k = idx & 255;
        Wt1[idx] = f2b(W1[k*128 + c]);
    } else if (b < 192){          // W2: 128x128
        int idx = (b-128)*256 + t; int c = idx >> 7, k = idx & 127;
        Wt2[idx] = f2b(W2[k*128 + c]);
    } else if (b < 256){          // W3: 128x128
        int idx = (b-192)*256 + t; int c = idx >> 7, k = idx & 127;
        Wt3[idx] = f2b(W3[k*128 + c]);
    } else {
        __shared__ int h[128];
        int bb = b - 256;
        if (t < 128) h[t] = 0;
        __syncthreads();
        int base = bb*1024 + t;
        #pragma unroll
        for (int i = 0; i < 4; i++) atomicAdd(&h[dst[base + i*256] >> 10], 1);
        __syncthreads();
        if (t < 128) hist[bb*128 + t] = h[t];
    }
}

// A2: per-bucket column exclusive scan over 1024 blocks -> baseRel[blk][bucket], total[bucket]
__global__ __launch_bounds__(256) void bin_scan(const int* __restrict__ hist,
                                                int* __restrict__ baseRel, int* __restrict__ total){
    int bk = blockIdx.x, t = threadIdx.x;   // 128 blocks
    int v[4]; int s = 0;
    #pragma unroll
    for (int i = 0; i < 4; i++){ v[i] = hist[(t*4+i)*128 + bk]; s += v[i]; }
    __shared__ int l[256];
    l[t] = s; __syncthreads();
    for (int off = 1; off < 256; off <<= 1){
        int u = (t >= off) ? l[t-off] : 0;
        __syncthreads();
        l[t] += u;
        __syncthreads();
    }
    int run = l[t] - s;
    #pragma unroll
    for (int i = 0; i < 4; i++){ baseRel[(t*4+i)*128 + bk] = run; run += v[i]; }
    if (t == 255) total[bk] = run;
}

// A2b: scan 128 bucket totals -> bstart (edge space), brow (col space incl self loops)
__global__ void bucket_scan(const int* __restrict__ total, int* __restrict__ bstart,
                            int* __restrict__ brow, int* __restrict__ row_ptr){
    int t = threadIdx.x;   // 128
    __shared__ int l[128];
    int v = total[t];
    l[t] = v; __syncthreads();
    for (int off = 1; off < 128; off <<= 1){
        int u = (t >= off) ? l[t-off] : 0;
        __syncthreads();
        l[t] += u;
        __syncthreads();
    }
    int e = l[t] - v;
    bstart[t] = e;
    brow[t] = e + t*1024;          // + self loops of preceding buckets
    if (t == 127) row_ptr[N_NODES] = TOT_EDG;
}

// A3: scatter (src,dst) into bucket-ordered array; per-block contiguous runs per bucket.
__global__ __launch_bounds__(256) void bin_scatter(const int* __restrict__ src, const int* __restrict__ dst,
                           const int* __restrict__ baseRel, const int* __restrict__ bstart,
                           uint2* __restrict__ binned){
    __shared__ int cur[128];
    __shared__ int bs[128];
    int b = blockIdx.x, t = threadIdx.x;
    if (t < 128){ cur[t] = baseRel[b*128 + t]; bs[t] = bstart[t]; }
    __syncthreads();
    #pragma unroll
    for (int i = 0; i < 4; i++){
        int e = b*1024 + i*256 + t;
        int s = src[e], d = dst[e];
        int bk = d >> 10;
        int r = atomicAdd(&cur[bk], 1);
        uint2 o; o.x = (u32)s; o.y = (u32)d;
        binned[bs[bk] + r] = o;
    }
}

// B: one block per bucket: LDS counts + LDS scan -> row_ptr, self loops, col scatter (L2-local window)
__global__ __launch_bounds__(256) void bucket_csr(const uint2* __restrict__ binned,
                           const int* __restrict__ bstart, const int* __restrict__ total,
                           const int* __restrict__ brow,
                           int* __restrict__ row_ptr, int* __restrict__ colb){
    int b = blockIdx.x, t = threadIdx.x;
    __shared__ int cnt[1024];
    __shared__ int l[256];
    int ebeg = bstart[b], ecnt = total[b], rbase = brow[b];
    for (int i = t; i < 1024; i += 256) cnt[i] = 1;      // self loop
    __syncthreads();
    for (int i = t; i < ecnt; i += 256){
        uint2 e = binned[ebeg + i];
        atomicAdd(&cnt[e.y & 1023], 1);
    }
    __syncthreads();
    int v0 = cnt[t*4], v1 = cnt[t*4+1], v2 = cnt[t*4+2], v3 = cnt[t*4+3];
    int s = v0+v1+v2+v3;
    l[t] = s; __syncthreads();
    for (int off = 1; off < 256; off <<= 1){
        int u = (t >= off) ? l[t-off] : 0;
        __syncthreads();
        l[t] += u;
        __syncthreads();
    }
    int excl = l[t] - s;
    int node0 = b*1024 + t*4;
    int p0 = rbase + excl;
    int p1 = p0 + v0, p2 = p1 + v1, p3 = p2 + v2;
    row_ptr[node0]   = p0; colb[p0] = node0;
    row_ptr[node0+1] = p1; colb[p1] = node0+1;
    row_ptr[node0+2] = p2; colb[p2] = node0+2;
    row_ptr[node0+3] = p3; colb[p3] = node0+3;
    __syncthreads();
    cnt[t*4] = p0+1; cnt[t*4+1] = p1+1; cnt[t*4+2] = p2+1; cnt[t*4+3] = p3+1;
    __syncthreads();
    for (int i = t; i < ecnt; i += 256){
        uint2 e = binned[ebeg + i];
        int p = atomicAdd(&cnt[e.y & 1023], 1);
        colb[p] = (int)e.x;
    }
}

// ---------------- MFMA GEMM, LDS-free node operand, fused es/ed epilogue ----------------
// D = W_frag(A-op) x node_frag(B-op). B-op fragment = 16 contiguous bf16 of the node row
// -> loaded straight from global (no LDS round trip, no per-iter barriers).
// Each wave owns 16 nodes (m16) and computes all 128 out_ch (8 tiles).
template<int K, bool AF32>
__global__ __launch_bounds__(256) void gat_gemm(const void* __restrict__ A_,
                                                const u16* __restrict__ Wt,   // [128][K]
                                                const float* __restrict__ asrc,
                                                const float* __restrict__ adst,
                                                u16* __restrict__ Hb,
                                                float* __restrict__ es, float* __restrict__ ed){
    constexpr int SW = 136;               // padded LDS k-stride (bf16 units)
    __shared__ u16 w[128*SW];             // one 128-wide k-chunk of Wt (~34 KB)
    const int t = threadIdx.x;
    const int wave = t >> 6, lane = t & 63, quad = lane >> 4, m16 = lane & 15;
    const long node = (long)blockIdx.x * 64 + wave*16 + m16;
    f4 acc[8] = {};                       // acc[tile]: out_ch = tile*16 + quad*4 + reg

    for (int chunk = 0; chunk < K; chunk += 128){
        if (chunk) __syncthreads();
        {   // stage Wt[:, chunk..chunk+128) into LDS, 128 B per thread
            int r = t >> 1;
            int half = (t & 1) << 6;
            const u16* src = Wt + (long)r*K + chunk + half;
            u16* dl = &w[r*SW + half];
            #pragma unroll
            for (int i = 0; i < 8; i++)
                *(uint4*)(dl + i*8) = *(const uint4*)(src + i*8);
        }
        __syncthreads();

        bh8 bf[4];
        if (AF32){
            const float* A = (const float*)A_ + node*(long)K + chunk;
            #pragma unroll
            for (int ks = 0; ks < 4; ks++){
                float4 f0 = *(const float4*)(A + ks*32 + quad*8);
                float4 f1 = *(const float4*)(A + ks*32 + quad*8 + 4);
                uint4 uv;
                uv.x = pk_rn(f0.x, f0.y); uv.y = pk_rn(f0.z, f0.w);
                uv.z = pk_rn(f1.x, f1.y); uv.w = pk_rn(f1.z, f1.w);
                bf[ks] = __builtin_bit_cast(bh8, uv);
            }
        } else {
            const u16* A = (const u16*)A_ + node*(long)K + chunk;
            #pragma unroll
            for (int ks = 0; ks < 4; ks++)
                bf[ks] = *(const bh8*)(A + ks*32 + quad*8);
        }
        #pragma unroll
        for (int tl = 0; tl < 8; tl++){
            #pragma unroll
            for (int ks = 0; ks < 4; ks++){
                bh8 af = *(const bh8*)&w[(tl*16 + m16)*SW + ks*32 + quad*8];
                acc[tl] = __builtin_amdgcn_mfma_f32_16x16x32_bf16(af, bf[ks], acc[tl], 0,0,0);
            }
        }
    }
    // epilogue: packed stores + fused es/ed
    float ps = 0.f, pd = 0.f;
    #pragma unroll
    for (int tl = 0; tl < 8; tl++){
        f4 a = acc[tl];
        float4 av = *(const float4*)(asrc + tl*16 + quad*4);
        float4 dv = *(const float4*)(adst + tl*16 + quad*4);
        ps += a.x*av.x + a.y*av.y + a.z*av.z + a.w*av.w;
        pd += a.x*dv.x + a.y*dv.y + a.z*dv.z + a.w*dv.w;
        uint2 o;
        o.x = pk_rn(a.x, a.y);
        o.y = pk_rn(a.z, a.w);
        *(uint2*)(Hb + node*128 + tl*16 + quad*4) = o;
    }
    ps += __shfl_xor(ps, 16); ps += __shfl_xor(ps, 32);
    pd += __shfl_xor(pd, 16); pd += __shfl_xor(pd, 32);
    if (quad == 0){ es[node] = ps; ed[node] = pd; }
}

// ---------------- softmax-weighted aggregation: wave/node, 4 groups x 16 lanes, 3-deep ----------------
// 12 row-gathers (3 KB) in flight per wave; a[8] keeps VGPR pressure low.
__global__ __launch_bounds__(256) void gat_agg(const u16* __restrict__ Hb,
                        const float* __restrict__ es, const float* __restrict__ ed,
                        const int* __restrict__ row_ptr, const int* __restrict__ colv,
                        const float* __restrict__ bias, u16* __restrict__ Xb){
    int t = threadIdx.x, wave = t >> 6, lane = t & 63;
    int grp = lane >> 4, cl = lane & 15;      // 4 edge-groups x 16 channel-lanes
    int n = blockIdx.x * 4 + wave;
    int beg = row_ptr[n], end = row_ptr[n+1];
    float edn = ed[n];
    float den = 0.f;
    float a[8] = {};
    int j = beg + grp;
    for (; j + 8 < end; j += 12){
        int s0 = colv[j], s1 = colv[j+4], s2 = colv[j+8];
        float q0 = es[s0] + edn, q1 = es[s1] + edn, q2 = es[s2] + edn;
        uint4 h0 = *(const uint4*)(Hb + (long)s0*128 + cl*8);
        uint4 h1 = *(const uint4*)(Hb + (long)s1*128 + cl*8);
        uint4 h2 = *(const uint4*)(Hb + (long)s2*128 + cl*8);
        q0 = fmaxf(q0, 0.f) + 0.2f*fminf(q0, 0.f);
        q1 = fmaxf(q1, 0.f) + 0.2f*fminf(q1, 0.f);
        q2 = fmaxf(q2, 0.f) + 0.2f*fminf(q2, 0.f);
        float x0 = __expf(q0), x1 = __expf(q1), x2 = __expf(q2);
        den += x0 + x1 + x2;
        a[0] += x0*bcf(h0.x << 16) + x1*bcf(h1.x << 16) + x2*bcf(h2.x << 16);
        a[1] += x0*bcf(h0.x & 0xffff0000u) + x1*bcf(h1.x & 0xffff0000u) + x2*bcf(h2.x & 0xffff0000u);
        a[2] += x0*bcf(h0.y << 16) + x1*bcf(h1.y << 16) + x2*bcf(h2.y << 16);
        a[3] += x0*bcf(h0.y & 0xffff0000u) + x1*bcf(h1.y & 0xffff0000u) + x2*bcf(h2.y & 0xffff0000u);
        a[4] += x0*bcf(h0.z << 16) + x1*bcf(h1.z << 16) + x2*bcf(h2.z << 16);
        a[5] += x0*bcf(h0.z & 0xffff0000u) + x1*bcf(h1.z & 0xffff0000u) + x2*bcf(h2.z & 0xffff0000u);
        a[6] += x0*bcf(h0.w << 16) + x1*bcf(h1.w << 16) + x2*bcf(h2.w << 16);
        a[7] += x0*bcf(h0.w & 0xffff0000u) + x1*bcf(h1.w & 0xffff0000u) + x2*bcf(h2.w & 0xffff0000u);
    }
    if (j + 4 < end){
        int s0 = colv[j], s1 = colv[j+4];
        float q0 = es[s0] + edn, q1 = es[s1] + edn;
        uint4 h0 = *(const uint4*)(Hb + (long)s0*128 + cl*8);
        uint4 h1 = *(const uint4*)(Hb + (long)s1*128 + cl*8);
        q0 = fmaxf(q0, 0.f) + 0.2f*fminf(q0, 0.f);
        q1 = fmaxf(q1, 0.f) + 0.2f*fminf(q1, 0.f);
        float x0 = __expf(q0), x1 = __expf(q1);
        den += x0 + x1;
        a[0] += x0*bcf(h0.x << 16) + x1*bcf(h1.x << 16);
        a[1] += x0*bcf(h0.x & 0xffff0000u) + x1*bcf(h1.x & 0xffff0000u);
        a[2] += x0*bcf(h0.y << 16) + x1*bcf(h1.y << 16);
        a[3] += x0*bcf(h0.y & 0xffff0000u) + x1*bcf(h1.y & 0xffff0000u);
        a[4] += x0*bcf(h0.z << 16) + x1*bcf(h1.z << 16);
        a[5] += x0*bcf(h0.z & 0xffff0000u) + x1*bcf(h1.z & 0xffff0000u);
        a[6] += x0*bcf(h0.w << 16) + x1*bcf(h1.w << 16);
        a[7] += x0*bcf(h0.w & 0xffff0000u) + x1*bcf(h1.w & 0xffff0000u);
    } else if (j < end){
        int s = colv[j];
        float e = es[s] + edn;
        e = fmaxf(e, 0.f) + 0.2f*fminf(e, 0.f);
        float ex = __expf(e);
        uint4 hv = *(const uint4*)(Hb + (long)s*128 + cl*8);
        den += ex;
        a[0] += ex * bcf(hv.x << 16);  a[1] += ex * bcf(hv.x & 0xffff0000u);
        a[2] += ex * bcf(hv.y << 16);  a[3] += ex * bcf(hv.y & 0xffff0000u);
        a[4] += ex * bcf(hv.z << 16);  a[5] += ex * bcf(hv.z & 0xffff0000u);
        a[6] += ex * bcf(hv.w << 16);  a[7] += ex * bcf(hv.w & 0xffff0000u);
    }
    #pragma unroll
    for (int k = 0; k < 8; k++){
        a[k] += __shfl_xor(a[k], 16);
        a[k] += __shfl_xor(a[k], 32);
    }
    den += __shfl_xor(den, 16); den += __shfl_xor(den, 32);
    if (grp == 0){
        float inv = 1.0f / (den + 1e-16f);
        float4 b0 = *(const float4*)(bias + cl*8);
        float4 b1 = *(const float4*)(bias + cl*8 + 4);
        uint4 ov;
        ov.x = pk_rn(fmaxf(a[0]*inv + b0.x, 0.f), fmaxf(a[1]*inv + b0.y, 0.f));
        ov.y = pk_rn(fmaxf(a[2]*inv + b0.z, 0.f), fmaxf(a[3]*inv + b0.w, 0.f));
        ov.z = pk_rn(fmaxf(a[4]*inv + b1.x, 0.f), fmaxf(a[5]*inv + b1.y, 0.f));
        ov.w = pk_rn(fmaxf(a[6]*inv + b1.z, 0.f), fmaxf(a[7]*inv + b1.w, 0.f));
        *(uint4*)(Xb + (long)n*128 + cl*8) = ov;
    }
}

// ---------------- partial per-graph max pool: block = 128 nodes ----------------
__global__ void pool_part(const u16* __restrict__ Xb, float* __restrict__ pooled8){
    int b = blockIdx.x;            // 1024 = G*8 segments
    int t = threadIdx.x;           // 256
    int wave = t >> 6, lane = t & 63, grp = lane >> 4, cl = lane & 15;
    long base = (long)b * 128;
    float m[8] = {};
    for (int i = 0; i < 8; i++){
        long node = base + wave*32 + i*4 + grp;
        uint4 hv = *(const uint4*)(Xb + node*128 + cl*8);
        m[0] = fmaxf(m[0], bcf(hv.x << 16));  m[1] = fmaxf(m[1], bcf(hv.x & 0xffff0000u));
        m[2] = fmaxf(m[2], bcf(hv.y << 16));  m[3] = fmaxf(m[3], bcf(hv.y & 0xffff0000u));
        m[4] = fmaxf(m[4], bcf(hv.z << 16));  m[5] = fmaxf(m[5], bcf(hv.z & 0xffff0000u));
        m[6] = fmaxf(m[6], bcf(hv.w << 16));  m[7] = fmaxf(m[7], bcf(hv.w & 0xffff0000u));
    }
    #pragma unroll
    for (int k = 0; k < 8; k++){
        m[k] = fmaxf(m[k], __shfl_xor(m[k], 16));
        m[k] = fmaxf(m[k], __shfl_xor(m[k], 32));
    }
    __shared__ float red[4][128];
    if (grp == 0){
        #pragma unroll
        for (int k = 0; k < 8; k++) red[wave][cl*8 + k] = m[k];
    }
    __syncthreads();
    if (t < 128){
        float v = fmaxf(fmaxf(red[0][t], red[1][t]), fmaxf(red[2][t], red[3][t]));
        pooled8[(long)b*128 + t] = v;
    }
}

// ---------------- tail: 8-way pool reduce, news, h0, eh/ee projections ----------------
__global__ void tail2(const float* __restrict__ x, const float* __restrict__ pooled8,
                      const float* __restrict__ Wn, const float* __restrict__ bn,
                      const float* __restrict__ W0, const float* __restrict__ b0,
                      const float* __restrict__ Wa1, const float* __restrict__ Wa2,
                      float* eh1, float* ee1, float* eh2, float* ee2){
    int g = blockIdx.x, c = threadIdx.x;  // 128 threads
    __shared__ float xr[256], pr[128], nr[128], hr[128];
    const float* xroot = x + (size_t)g * NPG * 256;   // root = first node of graph
    xr[c] = xroot[c]; xr[c+128] = xroot[c+128];
    {
        const float* pg = pooled8 + (long)g*8*128 + c;
        float v = pg[0];
        for (int s2 = 1; s2 < 8; s2++) v = fmaxf(v, pg[s2*128]);
        pr[c] = v;
    }
    __syncthreads();
    float a = bn[c];
    for (int k = 0; k < 256; k++) a += xr[k] * Wn[k*128 + c];
    a = fmaxf(a, 0.f);
    float b = b0[c];
    for (int k = 0; k < 128; k++) b += pr[k] * W0[k*128 + c];
    b = fmaxf(b, 0.f);
    nr[c] = a; hr[c] = b;
    __syncthreads();
    if (c < 64){
        int o = c; float s1 = 0.f, s2 = 0.f;
        for (int k = 0; k < 128; k++){ s1 += hr[k]*Wa1[k*64 + o]; s2 += nr[k]*Wa2[k*64 + o]; }
        eh1[g*64 + o] = s1; eh2[g*64 + o] = s2;
    } else {
        int o = c - 64; float s1 = 0.f, s2 = 0.f;
        for (int k = 0; k < 128; k++){ s1 += nr[k]*Wa1[(128+k)*64 + o]; s2 += hr[k]*Wa2[(128+k)*64 + o]; }
        ee1[g*64 + o] = s1; ee2[g*64 + o] = s2;
    }
}

// ---------------- tail: energies + final linear + sigmoid (block per row i) ----------------
__global__ void tail3(const float* __restrict__ eh1, const float* __restrict__ ee1,
                      const float* __restrict__ eh2, const float* __restrict__ ee2,
                      const float* __restrict__ ba1, const float* __restrict__ v1,
                      const float* __restrict__ ba2, const float* __restrict__ v2,
                      const float* __restrict__ Wl, const float* __restrict__ bl,
                      float* out){
    int i = blockIdx.x, t = threadIdx.x;   // 256 threads
    __shared__ float e1i[64], e2i[64], fh[128], fn[128];
    if (t < 64) e1i[t] = eh1[i*64 + t];
    else if (t < 128) e2i[t-64] = eh2[i*64 + (t-64)];
    __syncthreads();
    if (t < 128){
        int j = t; float s = 0.f;
        for (int o = 0; o < 64; o++) s += tanhf(e1i[o] + ee1[j*64+o] + ba1[o]) * v1[o];
        fh[j] = s;
    } else {
        int j = t - 128; float s = 0.f;
        for (int o = 0; o < 64; o++) s += tanhf(e2i[o] + ee2[j*64+o] + ba2[o]) * v2[o];
        fn[j] = s;
    }
    __syncthreads();
    if (t < 64){
        int o = t; float s = bl[o];
        for (int j = 0; j < 128; j++) s += fh[j]*Wl[j*64+o] + fn[j]*Wl[(128+j)*64+o];
        out[i*64 + o] = 1.0f / (1.0f + expf(-s));
    }
}

extern "C" void kernel_launch(void* const* d_in, const int* in_sizes, int n_in,
                              void* d_out, int out_size, void* d_ws, size_t ws_size,
                              hipStream_t stream){
    const float* x   = (const float*)d_in[0];
    const int* eidx  = (const int*)d_in[1];
    const int* esrc  = eidx;
    const int* edst  = eidx + N_EDGES;
    const float* W1  = (const float*)d_in[3];
    const float* as1 = (const float*)d_in[4];
    const float* ad1 = (const float*)d_in[5];
    const float* b1  = (const float*)d_in[6];
    const float* W2  = (const float*)d_in[7];
    const float* as2 = (const float*)d_in[8];
    const float* ad2 = (const float*)d_in[9];
    const float* b2  = (const float*)d_in[10];
    const float* W3  = (const float*)d_in[11];
    const float* as3 = (const float*)d_in[12];
    const float* ad3 = (const float*)d_in[13];
    const float* b3  = (const float*)d_in[14];
    const float* Wn  = (const float*)d_in[15];
    const float* bn  = (const float*)d_in[16];
    const float* W0  = (const float*)d_in[17];
    const float* b0  = (const float*)d_in[18];
    const float* Wl  = (const float*)d_in[19];
    const float* bl  = (const float*)d_in[20];
    const float* Wa1 = (const float*)d_in[21];
    const float* ba1 = (const float*)d_in[22];
    const float* v1  = (const float*)d_in[23];
    const float* Wa2 = (const float*)d_in[24];
    const float* ba2 = (const float*)d_in[25];
    const float* v2  = (const float*)d_in[26];
    float* out = (float*)d_out;

    char* p = (char*)d_ws;
    auto take = [&](size_t b)->char*{ char* q = p; p += (b + 255) & ~(size_t)255; return q; };
    u16* Hb      = (u16*)take((size_t)N_NODES*128*2);
    u16* Xb      = (u16*)take((size_t)N_NODES*128*2);
    float* es    = (float*)take((size_t)N_NODES*4);
    float* ed    = (float*)take((size_t)N_NODES*4);
    int* row_ptr = (int*)take((size_t)(N_NODES+1)*4);
    int* colb    = (int*)take((size_t)TOT_EDG*4);
    uint2* binned= (uint2*)take((size_t)N_EDGES*8);
    int* hist    = (int*)take((size_t)1024*128*4);
    int* baseRel = (int*)take((size_t)1024*128*4);
    int* total   = (int*)take(128*4);
    int* bstart  = (int*)take(128*4);
    int* brow    = (int*)take(128*4);
    u16* Wt1     = (u16*)take(128*256*2);
    u16* Wt2     = (u16*)take(128*128*2);
    u16* Wt3     = (u16*)take(128*128*2);
    float* pooled8=(float*)take((size_t)1024*128*4);
    float* eh1   = (float*)take(128*64*4);
    float* ee1   = (float*)take(128*64*4);
    float* eh2   = (float*)take(128*64*4);
    float* ee2   = (float*)take(128*64*4);

    // weight transposes + histogram, single launch
    wtrans_hist<<<1280, 256, 0, stream>>>(W1, W2, W3, Wt1, Wt2, Wt3, edst, hist);

    // binned CSR build (by dst, self-loop in slot 0)
    bin_scan<<<128, 256, 0, stream>>>(hist, baseRel, total);
    bucket_scan<<<1, 128, 0, stream>>>(total, bstart, brow, row_ptr);
    bin_scatter<<<1024, 256, 0, stream>>>(esrc, edst, baseRel, bstart, binned);
    bucket_csr<<<128, 256, 0, stream>>>(binned, bstart, total, brow, row_ptr, colb);

    // layer 1
    gat_gemm<256, true><<<N_NODES/64, 256, 0, stream>>>(x, Wt1, as1, ad1, Hb, es, ed);
    gat_agg<<<N_NODES/4, 256, 0, stream>>>(Hb, es, ed, row_ptr, colb, b1, Xb);
    // layer 2
    gat_gemm<128, false><<<N_NODES/64, 256, 0, stream>>>(Xb, Wt2, as2, ad2, Hb, es, ed);
    gat_agg<<<N_NODES/4, 256, 0, stream>>>(Hb, es, ed, row_ptr, colb, b2, Xb);
    // layer 3
    gat_gemm<128, false><<<N_NODES/64, 256, 0, stream>>>(Xb, Wt3, as3, ad3, Hb, es, ed);
    gat_agg<<<N_NODES/4, 256, 0, stream>>>(Hb, es, ed, row_ptr, colb, b3, Xb);

    // tail
    pool_part<<<1024, 256, 0, stream>>>(Xb, pooled8);
    tail2<<<G_GRAPHS, 128, 0, stream>>>(x, pooled8, Wn, bn, W0, b0, Wa1, Wa2, eh1, ee1, eh2, ee2);
    tail3<<<G_GRAPHS, 256, 0, stream>>>(eh1, ee1, eh2, ee2, ba1, v1, ba2, v2, Wl, bl, out);
}

// Round 7
// 574.043 us; speedup vs baseline: 1.0850x; 1.0415x over previous
//
#include <hip/hip_runtime.h>

#define N_NODES 131072
#define N_EDGES 1048576
#define TOT_EDG (N_NODES + N_EDGES)
#define G_GRAPHS 128
#define NPG 1024

typedef unsigned short u16;
typedef unsigned int u32;
typedef __attribute__((ext_vector_type(8))) short bh8;
typedef __attribute__((ext_vector_type(4))) float f4;

__device__ __forceinline__ float bcf(u32 u){ return __builtin_bit_cast(float, u); }
__device__ __forceinline__ u32 bcu(float f){ return __builtin_bit_cast(u32, f); }

// round-half-up bf16: (u + 0x8000) >> 16 ; pack pair with one v_perm_b32
__device__ __forceinline__ u16 f2b(float f){ return (u16)((bcu(f) + 0x8000u) >> 16); }
__device__ __forceinline__ u32 pk_rn(float lo, float hi){
    u32 a = bcu(lo) + 0x8000u;
    u32 b = bcu(hi) + 0x8000u;
    return __builtin_amdgcn_perm(b, a, 0x07060302u);   // D = {b.hi16, a.hi16}
}

// ---------------- fused: weight transposes (blocks 0..255) + edge histogram (256..1279) ----------------
__global__ __launch_bounds__(256) void wtrans_hist(const float* __restrict__ W1, const float* __restrict__ W2,
                           const float* __restrict__ W3,
                           u16* __restrict__ Wt1, u16* __restrict__ Wt2, u16* __restrict__ Wt3,
                           const int* __restrict__ dst, int* __restrict__ hist){
    int b = blockIdx.x, t = threadIdx.x;
    if (b < 128){                 // W1: 256x128 -> Wt1[128][256]
        int idx = b*256 + t; int c = idx >> 8, k = idx & 255;
        Wt1[idx] = f2b(W1[k*128 + c]);
    } else if (b < 192){          // W2: 128x128
        int idx = (b-128)*256 + t; int c = idx >> 7, k = idx & 127;
        Wt2[idx] = f2b(W2[k*128 + c]);
    } else if (b < 256){          // W3: 128x128
        int idx = (b-192)*256 + t; int c = idx >> 7, k = idx & 127;
        Wt3[idx] = f2b(W3[k*128 + c]);
    } else {
        __shared__ int h[128];
        int bb = b - 256;
        if (t < 128) h[t] = 0;
        __syncthreads();
        int base = bb*1024 + t;
        #pragma unroll
        for (int i = 0; i < 4; i++) atomicAdd(&h[dst[base + i*256] >> 10], 1);
        __syncthreads();
        if (t < 128) hist[bb*128 + t] = h[t];
    }
}

// A2: per-bucket column exclusive scan over 1024 blocks -> baseRel[blk][bucket], total[bucket]
__global__ __launch_bounds__(256) void bin_scan(const int* __restrict__ hist,
                                                int* __restrict__ baseRel, int* __restrict__ total){
    int bk = blockIdx.x, t = threadIdx.x;   // 128 blocks
    int v[4]; int s = 0;
    #pragma unroll
    for (int i = 0; i < 4; i++){ v[i] = hist[(t*4+i)*128 + bk]; s += v[i]; }
    __shared__ int l[256];
    l[t] = s; __syncthreads();
    for (int off = 1; off < 256; off <<= 1){
        int u = (t >= off) ? l[t-off] : 0;
        __syncthreads();
        l[t] += u;
        __syncthreads();
    }
    int run = l[t] - s;
    #pragma unroll
    for (int i = 0; i < 4; i++){ baseRel[(t*4+i)*128 + bk] = run; run += v[i]; }
    if (t == 255) total[bk] = run;
}

// A2b: scan 128 bucket totals -> bstart (edge space), brow (col space incl self loops)
__global__ void bucket_scan(const int* __restrict__ total, int* __restrict__ bstart,
                            int* __restrict__ brow, int* __restrict__ row_ptr){
    int t = threadIdx.x;   // 128
    __shared__ int l[128];
    int v = total[t];
    l[t] = v; __syncthreads();
    for (int off = 1; off < 128; off <<= 1){
        int u = (t >= off) ? l[t-off] : 0;
        __syncthreads();
        l[t] += u;
        __syncthreads();
    }
    int e = l[t] - v;
    bstart[t] = e;
    brow[t] = e + t*1024;          // + self loops of preceding buckets
    if (t == 127) row_ptr[N_NODES] = TOT_EDG;
}

// A3: scatter (src,dst) into bucket-ordered array; per-block contiguous runs per bucket.
__global__ __launch_bounds__(256) void bin_scatter(const int* __restrict__ src, const int* __restrict__ dst,
                           const int* __restrict__ baseRel, const int* __restrict__ bstart,
                           uint2* __restrict__ binned){
    __shared__ int cur[128];
    __shared__ int bs[128];
    int b = blockIdx.x, t = threadIdx.x;
    if (t < 128){ cur[t] = baseRel[b*128 + t]; bs[t] = bstart[t]; }
    __syncthreads();
    #pragma unroll
    for (int i = 0; i < 4; i++){
        int e = b*1024 + i*256 + t;
        int s = src[e], d = dst[e];
        int bk = d >> 10;
        int r = atomicAdd(&cur[bk], 1);
        uint2 o; o.x = (u32)s; o.y = (u32)d;
        binned[bs[bk] + r] = o;
    }
}

// B: one block per bucket: LDS counts + LDS scan -> row_ptr, self loops, col scatter (L2-local window)
__global__ __launch_bounds__(256) void bucket_csr(const uint2* __restrict__ binned,
                           const int* __restrict__ bstart, const int* __restrict__ total,
                           const int* __restrict__ brow,
                           int* __restrict__ row_ptr, int* __restrict__ colb){
    int b = blockIdx.x, t = threadIdx.x;
    __shared__ int cnt[1024];
    __shared__ int l[256];
    int ebeg = bstart[b], ecnt = total[b], rbase = brow[b];
    for (int i = t; i < 1024; i += 256) cnt[i] = 1;      // self loop
    __syncthreads();
    for (int i = t; i < ecnt; i += 256){
        uint2 e = binned[ebeg + i];
        atomicAdd(&cnt[e.y & 1023], 1);
    }
    __syncthreads();
    int v0 = cnt[t*4], v1 = cnt[t*4+1], v2 = cnt[t*4+2], v3 = cnt[t*4+3];
    int s = v0+v1+v2+v3;
    l[t] = s; __syncthreads();
    for (int off = 1; off < 256; off <<= 1){
        int u = (t >= off) ? l[t-off] : 0;
        __syncthreads();
        l[t] += u;
        __syncthreads();
    }
    int excl = l[t] - s;
    int node0 = b*1024 + t*4;
    int p0 = rbase + excl;
    int p1 = p0 + v0, p2 = p1 + v1, p3 = p2 + v2;
    row_ptr[node0]   = p0; colb[p0] = node0;
    row_ptr[node0+1] = p1; colb[p1] = node0+1;
    row_ptr[node0+2] = p2; colb[p2] = node0+2;
    row_ptr[node0+3] = p3; colb[p3] = node0+3;
    __syncthreads();
    cnt[t*4] = p0+1; cnt[t*4+1] = p1+1; cnt[t*4+2] = p2+1; cnt[t*4+3] = p3+1;
    __syncthreads();
    for (int i = t; i < ecnt; i += 256){
        uint2 e = binned[ebeg + i];
        int p = atomicAdd(&cnt[e.y & 1023], 1);
        colb[p] = (int)e.x;
    }
}

// ---------------- MFMA GEMM: weight in LDS, node operand from global, 2 node-groups ----------------
// D = W_frag(A-op) x node_frag(B-op). Per 128-wide K-chunk: wave issues ALL node loads for
// BOTH groups (8/16 x 16B in flight), then 64 MFMAs -> latency hidden across 16 waves/CU.
template<int K, bool AF32>
__global__ __launch_bounds__(256) void gat_gemm(const void* __restrict__ A_,
                                                const u16* __restrict__ Wt,   // [128][K]
                                                const float* __restrict__ asrc,
                                                const float* __restrict__ adst,
                                                u16* __restrict__ Hb,
                                                float* __restrict__ es, float* __restrict__ ed){
    constexpr int SW = 136;               // padded LDS k-stride for one 128-chunk (bf16 units)
    __shared__ u16 w[128*SW];             // 34816 B -> 4 blocks/CU
    const int t = threadIdx.x;
    const int wave = t >> 6, lane = t & 63, quad = lane >> 4, m16 = lane & 15;
    const long nodeBase = (long)blockIdx.x * 128 + wave*32;   // 2 groups x 16 nodes per wave
    f4 acc[2][8] = {};                    // acc[group][tile]

    for (int chunk = 0; chunk < K; chunk += 128){
        if (chunk) __syncthreads();
        {   // stage Wt[:, chunk..chunk+128) into LDS, 128 B per thread
            int r = t >> 1;
            int half = (t & 1) << 6;
            const u16* src = Wt + (long)r*K + chunk + half;
            u16* dl = &w[r*SW + half];
            #pragma unroll
            for (int i = 0; i < 8; i++)
                *(uint4*)(dl + i*8) = *(const uint4*)(src + i*8);
        }
        __syncthreads();

        bh8 bf[2][4];
        if (AF32){
            float4 raw[2][4][2];
            #pragma unroll
            for (int g = 0; g < 2; g++){
                const float* A = (const float*)A_ + (nodeBase + g*16 + m16)*(long)K + chunk;
                #pragma unroll
                for (int ks = 0; ks < 4; ks++){
                    raw[g][ks][0] = *(const float4*)(A + ks*32 + quad*8);
                    raw[g][ks][1] = *(const float4*)(A + ks*32 + quad*8 + 4);
                }
            }
            #pragma unroll
            for (int g = 0; g < 2; g++)
            #pragma unroll
            for (int ks = 0; ks < 4; ks++){
                uint4 uv;
                uv.x = pk_rn(raw[g][ks][0].x, raw[g][ks][0].y);
                uv.y = pk_rn(raw[g][ks][0].z, raw[g][ks][0].w);
                uv.z = pk_rn(raw[g][ks][1].x, raw[g][ks][1].y);
                uv.w = pk_rn(raw[g][ks][1].z, raw[g][ks][1].w);
                bf[g][ks] = __builtin_bit_cast(bh8, uv);
            }
        } else {
            #pragma unroll
            for (int g = 0; g < 2; g++){
                const u16* A = (const u16*)A_ + (nodeBase + g*16 + m16)*(long)K + chunk;
                #pragma unroll
                for (int ks = 0; ks < 4; ks++)
                    bf[g][ks] = *(const bh8*)(A + ks*32 + quad*8);
            }
        }
        #pragma unroll
        for (int g = 0; g < 2; g++)
        #pragma unroll
        for (int tl = 0; tl < 8; tl++){
            #pragma unroll
            for (int ks = 0; ks < 4; ks++){
                bh8 af = *(const bh8*)&w[(tl*16 + m16)*SW + ks*32 + quad*8];
                acc[g][tl] = __builtin_amdgcn_mfma_f32_16x16x32_bf16(af, bf[g][ks], acc[g][tl], 0,0,0);
            }
        }
    }
    // epilogue per group: packed stores + fused es/ed
    #pragma unroll
    for (int g = 0; g < 2; g++){
        long node = nodeBase + g*16 + m16;
        float ps = 0.f, pd = 0.f;
        #pragma unroll
        for (int tl = 0; tl < 8; tl++){
            f4 a = acc[g][tl];
            float4 av = *(const float4*)(asrc + tl*16 + quad*4);
            float4 dv = *(const float4*)(adst + tl*16 + quad*4);
            ps += a.x*av.x + a.y*av.y + a.z*av.z + a.w*av.w;
            pd += a.x*dv.x + a.y*dv.y + a.z*dv.z + a.w*dv.w;
            uint2 o;
            o.x = pk_rn(a.x, a.y);
            o.y = pk_rn(a.z, a.w);
            *(uint2*)(Hb + node*128 + tl*16 + quad*4) = o;
        }
        ps += __shfl_xor(ps, 16); ps += __shfl_xor(ps, 32);
        pd += __shfl_xor(pd, 16); pd += __shfl_xor(pd, 32);
        if (quad == 0){ es[node] = ps; ed[node] = pd; }
    }
}

// ---------------- softmax-weighted aggregation: wave/node, 4 groups x 16 lanes, 3-deep ----------------
__global__ __launch_bounds__(256) void gat_agg(const u16* __restrict__ Hb,
                        const float* __restrict__ es, const float* __restrict__ ed,
                        const int* __restrict__ row_ptr, const int* __restrict__ colv,
                        const float* __restrict__ bias, u16* __restrict__ Xb){
    int t = threadIdx.x, wave = t >> 6, lane = t & 63;
    int grp = lane >> 4, cl = lane & 15;      // 4 edge-groups x 16 channel-lanes
    int n = blockIdx.x * 4 + wave;
    int beg = row_ptr[n], end = row_ptr[n+1];
    float edn = ed[n];
    float den = 0.f;
    float a[8] = {};
    int j = beg + grp;
    for (; j + 8 < end; j += 12){
        int s0 = colv[j], s1 = colv[j+4], s2 = colv[j+8];
        float q0 = es[s0] + edn, q1 = es[s1] + edn, q2 = es[s2] + edn;
        uint4 h0 = *(const uint4*)(Hb + (long)s0*128 + cl*8);
        uint4 h1 = *(const uint4*)(Hb + (long)s1*128 + cl*8);
        uint4 h2 = *(const uint4*)(Hb + (long)s2*128 + cl*8);
        q0 = fmaxf(q0, 0.f) + 0.2f*fminf(q0, 0.f);
        q1 = fmaxf(q1, 0.f) + 0.2f*fminf(q1, 0.f);
        q2 = fmaxf(q2, 0.f) + 0.2f*fminf(q2, 0.f);
        float x0 = __expf(q0), x1 = __expf(q1), x2 = __expf(q2);
        den += x0 + x1 + x2;
        a[0] += x0*bcf(h0.x << 16) + x1*bcf(h1.x << 16) + x2*bcf(h2.x << 16);
        a[1] += x0*bcf(h0.x & 0xffff0000u) + x1*bcf(h1.x & 0xffff0000u) + x2*bcf(h2.x & 0xffff0000u);
        a[2] += x0*bcf(h0.y << 16) + x1*bcf(h1.y << 16) + x2*bcf(h2.y << 16);
        a[3] += x0*bcf(h0.y & 0xffff0000u) + x1*bcf(h1.y & 0xffff0000u) + x2*bcf(h2.y & 0xffff0000u);
        a[4] += x0*bcf(h0.z << 16) + x1*bcf(h1.z << 16) + x2*bcf(h2.z << 16);
        a[5] += x0*bcf(h0.z & 0xffff0000u) + x1*bcf(h1.z & 0xffff0000u) + x2*bcf(h2.z & 0xffff0000u);
        a[6] += x0*bcf(h0.w << 16) + x1*bcf(h1.w << 16) + x2*bcf(h2.w << 16);
        a[7] += x0*bcf(h0.w & 0xffff0000u) + x1*bcf(h1.w & 0xffff0000u) + x2*bcf(h2.w & 0xffff0000u);
    }
    if (j + 4 < end){
        int s0 = colv[j], s1 = colv[j+4];
        float q0 = es[s0] + edn, q1 = es[s1] + edn;
        uint4 h0 = *(const uint4*)(Hb + (long)s0*128 + cl*8);
        uint4 h1 = *(const uint4*)(Hb + (long)s1*128 + cl*8);
        q0 = fmaxf(q0, 0.f) + 0.2f*fminf(q0, 0.f);
        q1 = fmaxf(q1, 0.f) + 0.2f*fminf(q1, 0.f);
        float x0 = __expf(q0), x1 = __expf(q1);
        den += x0 + x1;
        a[0] += x0*bcf(h0.x << 16) + x1*bcf(h1.x << 16);
        a[1] += x0*bcf(h0.x & 0xffff0000u) + x1*bcf(h1.x & 0xffff0000u);
        a[2] += x0*bcf(h0.y << 16) + x1*bcf(h1.y << 16);
        a[3] += x0*bcf(h0.y & 0xffff0000u) + x1*bcf(h1.y & 0xffff0000u);
        a[4] += x0*bcf(h0.z << 16) + x1*bcf(h1.z << 16);
        a[5] += x0*bcf(h0.z & 0xffff0000u) + x1*bcf(h1.z & 0xffff0000u);
        a[6] += x0*bcf(h0.w << 16) + x1*bcf(h1.w << 16);
        a[7] += x0*bcf(h0.w & 0xffff0000u) + x1*bcf(h1.w & 0xffff0000u);
    } else if (j < end){
        int s = colv[j];
        float e = es[s] + edn;
        e = fmaxf(e, 0.f) + 0.2f*fminf(e, 0.f);
        float ex = __expf(e);
        uint4 hv = *(const uint4*)(Hb + (long)s*128 + cl*8);
        den += ex;
        a[0] += ex * bcf(hv.x << 16);  a[1] += ex * bcf(hv.x & 0xffff0000u);
        a[2] += ex * bcf(hv.y << 16);  a[3] += ex * bcf(hv.y & 0xffff0000u);
        a[4] += ex * bcf(hv.z << 16);  a[5] += ex * bcf(hv.z & 0xffff0000u);
        a[6] += ex * bcf(hv.w << 16);  a[7] += ex * bcf(hv.w & 0xffff0000u);
    }
    #pragma unroll
    for (int k = 0; k < 8; k++){
        a[k] += __shfl_xor(a[k], 16);
        a[k] += __shfl_xor(a[k], 32);
    }
    den += __shfl_xor(den, 16); den += __shfl_xor(den, 32);
    if (grp == 0){
        float inv = 1.0f / (den + 1e-16f);
        float4 b0 = *(const float4*)(bias + cl*8);
        float4 b1 = *(const float4*)(bias + cl*8 + 4);
        uint4 ov;
        ov.x = pk_rn(fmaxf(a[0]*inv + b0.x, 0.f), fmaxf(a[1]*inv + b0.y, 0.f));
        ov.y = pk_rn(fmaxf(a[2]*inv + b0.z, 0.f), fmaxf(a[3]*inv + b0.w, 0.f));
        ov.z = pk_rn(fmaxf(a[4]*inv + b1.x, 0.f), fmaxf(a[5]*inv + b1.y, 0.f));
        ov.w = pk_rn(fmaxf(a[6]*inv + b1.z, 0.f), fmaxf(a[7]*inv + b1.w, 0.f));
        *(uint4*)(Xb + (long)n*128 + cl*8) = ov;
    }
}

// ---------------- partial per-graph max pool: block = 128 nodes ----------------
__global__ void pool_part(const u16* __restrict__ Xb, float* __restrict__ pooled8){
    int b = blockIdx.x;            // 1024 = G*8 segments
    int t = threadIdx.x;           // 256
    int wave = t >> 6, lane = t & 63, grp = lane >> 4, cl = lane & 15;
    long base = (long)b * 128;
    float m[8] = {};
    for (int i = 0; i < 8; i++){
        long node = base + wave*32 + i*4 + grp;
        uint4 hv = *(const uint4*)(Xb + node*128 + cl*8);
        m[0] = fmaxf(m[0], bcf(hv.x << 16));  m[1] = fmaxf(m[1], bcf(hv.x & 0xffff0000u));
        m[2] = fmaxf(m[2], bcf(hv.y << 16));  m[3] = fmaxf(m[3], bcf(hv.y & 0xffff0000u));
        m[4] = fmaxf(m[4], bcf(hv.z << 16));  m[5] = fmaxf(m[5], bcf(hv.z & 0xffff0000u));
        m[6] = fmaxf(m[6], bcf(hv.w << 16));  m[7] = fmaxf(m[7], bcf(hv.w & 0xffff0000u));
    }
    #pragma unroll
    for (int k = 0; k < 8; k++){
        m[k] = fmaxf(m[k], __shfl_xor(m[k], 16));
        m[k] = fmaxf(m[k], __shfl_xor(m[k], 32));
    }
    __shared__ float red[4][128];
    if (grp == 0){
        #pragma unroll
        for (int k = 0; k < 8; k++) red[wave][cl*8 + k] = m[k];
    }
    __syncthreads();
    if (t < 128){
        float v = fmaxf(fmaxf(red[0][t], red[1][t]), fmaxf(red[2][t], red[3][t]));
        pooled8[(long)b*128 + t] = v;
    }
}

// ---------------- tail: 8-way pool reduce, news, h0, eh/ee projections ----------------
__global__ void tail2(const float* __restrict__ x, const float* __restrict__ pooled8,
                      const float* __restrict__ Wn, const float* __restrict__ bn,
                      const float* __restrict__ W0, const float* __restrict__ b0,
                      const float* __restrict__ Wa1, const float* __restrict__ Wa2,
                      float* eh1, float* ee1, float* eh2, float* ee2){
    int g = blockIdx.x, c = threadIdx.x;  // 128 threads
    __shared__ float xr[256], pr[128], nr[128], hr[128];
    const float* xroot = x + (size_t)g * NPG * 256;   // root = first node of graph
    xr[c] = xroot[c]; xr[c+128] = xroot[c+128];
    {
        const float* pg = pooled8 + (long)g*8*128 + c;
        float v = pg[0];
        for (int s2 = 1; s2 < 8; s2++) v = fmaxf(v, pg[s2*128]);
        pr[c] = v;
    }
    __syncthreads();
    float a = bn[c];
    for (int k = 0; k < 256; k++) a += xr[k] * Wn[k*128 + c];
    a = fmaxf(a, 0.f);
    float b = b0[c];
    for (int k = 0; k < 128; k++) b += pr[k] * W0[k*128 + c];
    b = fmaxf(b, 0.f);
    nr[c] = a; hr[c] = b;
    __syncthreads();
    if (c < 64){
        int o = c; float s1 = 0.f, s2 = 0.f;
        for (int k = 0; k < 128; k++){ s1 += hr[k]*Wa1[k*64 + o]; s2 += nr[k]*Wa2[k*64 + o]; }
        eh1[g*64 + o] = s1; eh2[g*64 + o] = s2;
    } else {
        int o = c - 64; float s1 = 0.f, s2 = 0.f;
        for (int k = 0; k < 128; k++){ s1 += nr[k]*Wa1[(128+k)*64 + o]; s2 += hr[k]*Wa2[(128+k)*64 + o]; }
        ee1[g*64 + o] = s1; ee2[g*64 + o] = s2;
    }
}

// ---------------- tail: energies + final linear + sigmoid (block per row i) ----------------
__global__ void tail3(const float* __restrict__ eh1, const float* __restrict__ ee1,
                      const float* __restrict__ eh2, const float* __restrict__ ee2,
                      const float* __restrict__ ba1, const float* __restrict__ v1,
                      const float* __restrict__ ba2, const float* __restrict__ v2,
                      const float* __restrict__ Wl, const float* __restrict__ bl,
                      float* out){
    int i = blockIdx.x, t = threadIdx.x;   // 256 threads
    __shared__ float e1i[64], e2i[64], fh[128], fn[128];
    if (t < 64) e1i[t] = eh1[i*64 + t];
    else if (t < 128) e2i[t-64] = eh2[i*64 + (t-64)];
    __syncthreads();
    if (t < 128){
        int j = t; float s = 0.f;
        for (int o = 0; o < 64; o++) s += tanhf(e1i[o] + ee1[j*64+o] + ba1[o]) * v1[o];
        fh[j] = s;
    } else {
        int j = t - 128; float s = 0.f;
        for (int o = 0; o < 64; o++) s += tanhf(e2i[o] + ee2[j*64+o] + ba2[o]) * v2[o];
        fn[j] = s;
    }
    __syncthreads();
    if (t < 64){
        int o = t; float s = bl[o];
        for (int j = 0; j < 128; j++) s += fh[j]*Wl[j*64+o] + fn[j]*Wl[(128+j)*64+o];
        out[i*64 + o] = 1.0f / (1.0f + expf(-s));
    }
}

extern "C" void kernel_launch(void* const* d_in, const int* in_sizes, int n_in,
                              void* d_out, int out_size, void* d_ws, size_t ws_size,
                              hipStream_t stream){
    const float* x   = (const float*)d_in[0];
    const int* eidx  = (const int*)d_in[1];
    const int* esrc  = eidx;
    const int* edst  = eidx + N_EDGES;
    const float* W1  = (const float*)d_in[3];
    const float* as1 = (const float*)d_in[4];
    const float* ad1 = (const float*)d_in[5];
    const float* b1  = (const float*)d_in[6];
    const float* W2  = (const float*)d_in[7];
    const float* as2 = (const float*)d_in[8];
    const float* ad2 = (const float*)d_in[9];
    const float* b2  = (const float*)d_in[10];
    const float* W3  = (const float*)d_in[11];
    const float* as3 = (const float*)d_in[12];
    const float* ad3 = (const float*)d_in[13];
    const float* b3  = (const float*)d_in[14];
    const float* Wn  = (const float*)d_in[15];
    const float* bn  = (const float*)d_in[16];
    const float* W0  = (const float*)d_in[17];
    const float* b0  = (const float*)d_in[18];
    const float* Wl  = (const float*)d_in[19];
    const float* bl  = (const float*)d_in[20];
    const float* Wa1 = (const float*)d_in[21];
    const float* ba1 = (const float*)d_in[22];
    const float* v1  = (const float*)d_in[23];
    const float* Wa2 = (const float*)d_in[24];
    const float* ba2 = (const float*)d_in[25];
    const float* v2  = (const float*)d_in[26];
    float* out = (float*)d_out;

    char* p = (char*)d_ws;
    auto take = [&](size_t b)->char*{ char* q = p; p += (b + 255) & ~(size_t)255; return q; };
    u16* Hb      = (u16*)take((size_t)N_NODES*128*2);
    u16* Xb      = (u16*)take((size_t)N_NODES*128*2);
    float* es    = (float*)take((size_t)N_NODES*4);
    float* ed    = (float*)take((size_t)N_NODES*4);
    int* row_ptr = (int*)take((size_t)(N_NODES+1)*4);
    int* colb    = (int*)take((size_t)TOT_EDG*4);
    uint2* binned= (uint2*)take((size_t)N_EDGES*8);
    int* hist    = (int*)take((size_t)1024*128*4);
    int* baseRel = (int*)take((size_t)1024*128*4);
    int* total   = (int*)take(128*4);
    int* bstart  = (int*)take(128*4);
    int* brow    = (int*)take(128*4);
    u16* Wt1     = (u16*)take(128*256*2);
    u16* Wt2     = (u16*)take(128*128*2);
    u16* Wt3     = (u16*)take(128*128*2);
    float* pooled8=(float*)take((size_t)1024*128*4);
    float* eh1   = (float*)take(128*64*4);
    float* ee1   = (float*)take(128*64*4);
    float* eh2   = (float*)take(128*64*4);
    float* ee2   = (float*)take(128*64*4);

    // weight transposes + histogram, single launch
    wtrans_hist<<<1280, 256, 0, stream>>>(W1, W2, W3, Wt1, Wt2, Wt3, edst, hist);

    // binned CSR build (by dst, self-loop in slot 0)
    bin_scan<<<128, 256, 0, stream>>>(hist, baseRel, total);
    bucket_scan<<<1, 128, 0, stream>>>(total, bstart, brow, row_ptr);
    bin_scatter<<<1024, 256, 0, stream>>>(esrc, edst, baseRel, bstart, binned);
    bucket_csr<<<128, 256, 0, stream>>>(binned, bstart, total, brow, row_ptr, colb);

    // layer 1
    gat_gemm<256, true><<<N_NODES/128, 256, 0, stream>>>(x, Wt1, as1, ad1, Hb, es, ed);
    gat_agg<<<N_NODES/4, 256, 0, stream>>>(Hb, es, ed, row_ptr, colb, b1, Xb);
    // layer 2
    gat_gemm<128, false><<<N_NODES/128, 256, 0, stream>>>(Xb, Wt2, as2, ad2, Hb, es, ed);
    gat_agg<<<N_NODES/4, 256, 0, stream>>>(Hb, es, ed, row_ptr, colb, b2, Xb);
    // layer 3
    gat_gemm<128, false><<<N_NODES/128, 256, 0, stream>>>(Xb, Wt3, as3, ad3, Hb, es, ed);
    gat_agg<<<N_NODES/4, 256, 0, stream>>>(Hb, es, ed, row_ptr, colb, b3, Xb);

    // tail
    pool_part<<<1024, 256, 0, stream>>>(Xb, pooled8);
    tail2<<<G_GRAPHS, 128, 0, stream>>>(x, pooled8, Wn, bn, W0, b0, Wa1, Wa2, eh1, ee1, eh2, ee2);
    tail3<<<G_GRAPHS, 256, 0, stream>>>(eh1, ee1, eh2, ee2, ba1, v1, ba2, v2, Wl, bl, out);
}